// Round 7
// baseline (347.557 us; speedup 1.0000x reference)
//
#include <hip/hip_runtime.h>

#define B_ 256
#define N_IN 1152
#define N_OUT 10
#define OJ 160                     // N_OUT * D_OUT
#define SN (B_*OJ)                 // 40960
#define LOG2E 1.44269504088896340736f
#define NSG 48                     // n supergroups (partials)
#define NPB (N_IN/NSG)             // 24 n per block
#define NPW (NPB/4)                // 6 n per wave
#define TOTB (NSG*16)              // 768 blocks per pass
#define FINB 16                    // finisher blocks
#define SLICE (SN/FINB)            // 2560 elements per finisher

typedef __attribute__((ext_vector_type(8))) short bf16x8;
typedef __attribute__((ext_vector_type(4))) float f32x4;

#define NW_ELEMS (N_IN*N_OUT*16)   // 184320 rows of 8 (W)
#define NX_ELEMS (B_*N_IN)         // 294912 rows of 8 (x)
#define NWB (NW_ELEMS/256)         // 720 W-pack blocks
#define NTILES ((N_IN/16)*(B_/16)) // 1152 x-transpose tiles

// ---- bf16 split helpers (RNE) ----
__device__ __forceinline__ unsigned short f2bf(float f) {
  unsigned u = __float_as_uint(f);
  u += 0x7fffu + ((u >> 16) & 1u);
  return (unsigned short)(u >> 16);
}
__device__ __forceinline__ float bf2f(unsigned short s) {
  return __uint_as_float(((unsigned)s) << 16);
}
__device__ __forceinline__ void split8(const float* p, bf16x8& vh, bf16x8& vl) {
  const float4 a = *(const float4*)p;
  const float4 b = *(const float4*)(p + 4);
  const float w[8] = {a.x,a.y,a.z,a.w,b.x,b.y,b.z,b.w};
#pragma unroll
  for (int e=0;e<8;e++){
    unsigned short hh = f2bf(w[e]);
    vh[e] = (short)hh;
    vl[e] = (short)f2bf(w[e] - bf2f(hh));
  }
}

// ---- DPP rotate-reduce over a 16-lane row ----
template<int CTRL>
__device__ __forceinline__ float dpp_add(float xx) {
  int y = __builtin_amdgcn_mov_dpp(__float_as_int(xx), CTRL, 0xF, 0xF, false);
  return xx + __int_as_float(y);
}
__device__ __forceinline__ float row_sum16(float xx) {
  xx = dpp_add<0x128>(xx); xx = dpp_add<0x124>(xx);
  xx = dpp_add<0x122>(xx); xx = dpp_add<0x121>(xx);
  return xx;
}
__device__ __forceinline__ float squash_elem(float t) {
  const float sq = row_sum16(t * t);
  return t * (sq / (1.f + sq)) * rsqrtf(sq + 1e-8f);
}

// ---- pack: W linear; x via LDS-transposed 16x16 tiles -> [n][b]; zero counters ----
__global__ __launch_bounds__(256) void pack_all(const float* __restrict__ W,
                                                const float* __restrict__ x,
                                                short* __restrict__ WH, short* __restrict__ WL,
                                                short* __restrict__ XH, short* __restrict__ XL,
                                                int* __restrict__ cnt) {
  const int bid = blockIdx.x, tid = threadIdx.x;
  if (bid == 0 && tid < 48) cnt[tid] = 0;
  if (bid < NWB) {
    const int t = bid*256 + tid;
    bf16x8 vh, vl; split8(W + (size_t)t*8, vh, vl);
    ((bf16x8*)WH)[t] = vh; ((bf16x8*)WL)[t] = vl;
  } else {
    __shared__ bf16x8 TH[16*17], TL[16*17];
    const int tile = bid - NWB;
    const int nt = tile >> 4, bt = tile & 15;
    const int nn = tid & 15, bb = tid >> 4;        // n fastest: coalesced reads
    bf16x8 vh, vl;
    split8(x + ((size_t)(bt*16+bb)*N_IN + nt*16+nn)*8, vh, vl);
    TH[nn*17 + bb] = vh; TL[nn*17 + bb] = vl;
    __syncthreads();
    const int bb2 = tid & 15, nn2 = tid >> 4;      // b fastest: coalesced writes
    const size_t o = (size_t)(nt*16+nn2)*B_ + bt*16 + bb2;
    ((bf16x8*)XH)[o] = TH[nn2*17 + bb2];
    ((bf16x8*)XL)[o] = TL[nn2*17 + bb2];
  }
}

// K-chunk trick: one 16x16x32 MFMA; lane's K-chunk c=l>>4 pulls A from
// [WH,WL,WH,WL] and B from [XH,XH,XL,XL] => exact (Wh+Wl)(xh+xl).
// C layout: col=lane&15=b, row=c*4+e=j.
// MODE 0: uniform coupling, finish -> v1 = squash(0.1 s)*log2e
// MODE 1: logits u.v1,      finish -> v12 = v1 + squash(s)*log2e
// MODE 2: logits u.v12,     finish -> out = squash(s)
template<int MODE>
__global__ __launch_bounds__(256) void caps_pass(
    const short* __restrict__ WH, const short* __restrict__ WL,
    const short* __restrict__ XH, const short* __restrict__ XL,
    const float* __restrict__ veff, float* __restrict__ P,
    const float* __restrict__ vprev, float* __restrict__ vout,
    int* __restrict__ cnt) {
  __shared__ f32x4 red[3*640];                    // 30 KB, conflict-free layout
  __shared__ int ticket_s;
  const int tid = threadIdx.x, w = tid >> 6, l = tid & 63;
  const int bb = l & 15, c = l >> 4;
  const int sg = blockIdx.x, bg = blockIdx.y;
  const int b0 = bg*16;
  const int n0 = sg*NPB + w*NPW;
  const short* Abase = (c & 1)  ? WL : WH;
  const short* Bbase = (c >> 1) ? XL : XH;

  const f32x4 zz = {0.f,0.f,0.f,0.f};
  f32x4 acc[N_OUT], vj[N_OUT];
#pragma unroll
  for (int o=0;o<N_OUT;o++) acc[o] = zz;
  if (MODE != 0) {
    const float* vp = &veff[(size_t)(b0+bb)*OJ + c*4];
#pragma unroll
    for (int o=0;o<N_OUT;o++) vj[o] = *(const f32x4*)&vp[o*16];
  }

  for (int nn=0; nn<NPW; ++nn) {
    const int n = n0 + nn;
    const bf16x8 bfrag = *(const bf16x8*)&Bbase[((size_t)n*B_ + b0 + bb)*8];
    const short* Ap = &Abase[(size_t)n*1280 + bb*8];
    if (MODE == 0) {
#pragma unroll
      for (int o=0;o<N_OUT;o++) {
        const bf16x8 afrag = *(const bf16x8*)&Ap[o*128];
        acc[o] = __builtin_amdgcn_mfma_f32_16x16x32_bf16(afrag, bfrag, acc[o], 0,0,0);
      }
    } else {
      f32x4 u[N_OUT];
#pragma unroll
      for (int o=0;o<N_OUT;o++) {
        const bf16x8 afrag = *(const bf16x8*)&Ap[o*128];
        u[o] = __builtin_amdgcn_mfma_f32_16x16x32_bf16(afrag, bfrag, zz, 0,0,0);
      }
      float ez[N_OUT], Z = 0.f;
#pragma unroll
      for (int o=0;o<N_OUT;o++) {
        float t = u[o][0]*vj[o][0] + u[o][1]*vj[o][1]
                + u[o][2]*vj[o][2] + u[o][3]*vj[o][3];
        t += __shfl_xor(t, 16);
        t += __shfl_xor(t, 32);
        ez[o] = exp2f(t);                          // veff stored in log2 domain
        Z += ez[o];
      }
      const float invZ = 1.f / Z;
#pragma unroll
      for (int o=0;o<N_OUT;o++) acc[o] += (ez[o]*invZ) * u[o];
    }
  }

  // 4-wave LDS tree: lane-contiguous 16B slots -> no bank conflicts
  if (w) {
#pragma unroll
    for (int o=0;o<N_OUT;o++) red[(w-1)*640 + o*64 + l] = acc[o];
  }
  __syncthreads();
  if (!w) {
#pragma unroll
    for (int o=0;o<N_OUT;o++)
      acc[o] += red[o*64+l] + red[640+o*64+l] + red[1280+o*64+l];
    float* Pp = &P[(size_t)sg*SN + (size_t)(b0+bb)*OJ + c*4];
#pragma unroll
    for (int o=0;o<N_OUT;o++) *(f32x4*)&Pp[o*16] = acc[o];
  }

  // ---- last-FINB-blocks fused finish ----
  __threadfence();                                 // release: P visible device-wide
  if (tid == 0) ticket_s = atomicAdd(cnt, 1);
  __syncthreads();
  const int rank = ticket_s - (TOTB - FINB);
  if (rank < 0 || rank >= FINB) return;            // upper guard: rocprof replay safety
  if (tid == 0) {
    while (__hip_atomic_load(cnt, __ATOMIC_ACQUIRE, __HIP_MEMORY_SCOPE_AGENT) < TOTB)
      __builtin_amdgcn_s_sleep(2);
  }
  __syncthreads();
  __threadfence();                                 // acquire: see all blocks' P

  const int base = rank*SLICE + tid;               // 16-lane aligned -> row_sum16 ok
  float s[10];
#pragma unroll
  for (int e=0;e<10;e++) s[e] = 0.f;
  for (int g=0; g<NSG; ++g) {
    const float* Pg = &P[(size_t)g*SN + base];
#pragma unroll
    for (int e=0;e<10;e++) s[e] += Pg[256*e];
  }
#pragma unroll
  for (int e=0;e<10;e++) {
    float t = s[e] * (MODE == 0 ? 0.1f : 1.f);
    float v = squash_elem(t) * (MODE == 2 ? 1.f : LOG2E);
    if (MODE == 1) v += vprev[base + 256*e];
    vout[base + 256*e] = v;
  }
}

extern "C" void kernel_launch(void* const* d_in, const int* in_sizes, int n_in,
                              void* d_out, int out_size, void* d_ws, size_t ws_size,
                              hipStream_t stream) {
  const float* x = (const float*)d_in[0];   // (256,1152,8)
  const float* W = (const float*)d_in[1];   // (1,1152,10,16,8)
  float* out = (float*)d_out;               // (256,10,16)

  float* P   = (float*)d_ws;                // NSG*SN floats = 7.9 MB
  float* v1  = P  + (size_t)NSG*SN;         // stored * log2e
  float* v12 = v1 + SN;                     // stored * log2e
  int*  cnt  = (int*)(v12 + SN);            // 48 ints (3 counters, padded)
  short* WH = (short*)(cnt + 64);
  short* WL = WH + (size_t)NW_ELEMS*8;
  short* XH = WL + (size_t)NW_ELEMS*8;
  short* XL = XH + (size_t)NX_ELEMS*8;      // total ws ~= 23.5 MB

  pack_all<<<NWB + NTILES, 256, 0, stream>>>(W, x, WH, WL, XH, XL, cnt);

  const dim3 pg(NSG, 16), pb(256);
  caps_pass<0><<<pg, pb, 0, stream>>>(WH, WL, XH, XL, nullptr, P, nullptr, v1,  cnt);
  caps_pass<1><<<pg, pb, 0, stream>>>(WH, WL, XH, XL, v1,      P, v1,      v12, cnt + 16);
  caps_pass<2><<<pg, pb, 0, stream>>>(WH, WL, XH, XL, v12,     P, nullptr, out, cnt + 32);
}

// Round 8
// 101.895 us; speedup vs baseline: 3.4109x; 3.4109x over previous
//
#include <hip/hip_runtime.h>

#define B_ 256
#define N_IN 1152
#define N_OUT 10
#define OJ 160                     // N_OUT * D_OUT
#define SN (B_*OJ)                 // 40960
#define LOG2E 1.44269504088896340736f
#define NSG 16                     // n supergroups (partials)
#define NPB (N_IN/NSG)             // 72 n per block
#define NPW (NPB/8)                // 9 n per wave (8 waves)

typedef __attribute__((ext_vector_type(8))) short bf16x8;
typedef __attribute__((ext_vector_type(4))) float f32x4;

#define NW_ELEMS (N_IN*N_OUT*16)   // 184320 rows of 8 (W)
#define NX_ELEMS (B_*N_IN)         // 294912 rows of 8 (x)
#define NWB (NW_ELEMS/256)         // 720 W-pack blocks
#define NTILES ((N_IN/16)*(B_/16)) // 1152 x-transpose tiles

// ---- bf16 split helpers (RNE) ----
__device__ __forceinline__ unsigned short f2bf(float f) {
  unsigned u = __float_as_uint(f);
  u += 0x7fffu + ((u >> 16) & 1u);
  return (unsigned short)(u >> 16);
}
__device__ __forceinline__ float bf2f(unsigned short s) {
  return __uint_as_float(((unsigned)s) << 16);
}
__device__ __forceinline__ void split8(const float* p, bf16x8& vh, bf16x8& vl) {
  const float4 a = *(const float4*)p;
  const float4 b = *(const float4*)(p + 4);
  const float w[8] = {a.x,a.y,a.z,a.w,b.x,b.y,b.z,b.w};
#pragma unroll
  for (int e=0;e<8;e++){
    unsigned short hh = f2bf(w[e]);
    vh[e] = (short)hh;
    vl[e] = (short)f2bf(w[e] - bf2f(hh));
  }
}

// ---- DPP rotate-reduce over a 16-lane row ----
template<int CTRL>
__device__ __forceinline__ float dpp_add(float xx) {
  int y = __builtin_amdgcn_mov_dpp(__float_as_int(xx), CTRL, 0xF, 0xF, false);
  return xx + __int_as_float(y);
}
__device__ __forceinline__ float row_sum16(float xx) {
  xx = dpp_add<0x128>(xx); xx = dpp_add<0x124>(xx);
  xx = dpp_add<0x122>(xx); xx = dpp_add<0x121>(xx);
  return xx;
}
__device__ __forceinline__ float squash_elem(float t) {
  const float sq = row_sum16(t * t);
  return t * (sq / (1.f + sq)) * rsqrtf(sq + 1e-8f);
}

// ---- pack: W linear; x via LDS-transposed 16x16 tiles -> [n][b] ----
__global__ __launch_bounds__(256) void pack_all(const float* __restrict__ W,
                                                const float* __restrict__ x,
                                                short* __restrict__ WH, short* __restrict__ WL,
                                                short* __restrict__ XH, short* __restrict__ XL) {
  const int bid = blockIdx.x, tid = threadIdx.x;
  if (bid < NWB) {
    const int t = bid*256 + tid;
    bf16x8 vh, vl; split8(W + (size_t)t*8, vh, vl);
    ((bf16x8*)WH)[t] = vh; ((bf16x8*)WL)[t] = vl;
  } else {
    __shared__ bf16x8 TH[16*17], TL[16*17];
    const int tile = bid - NWB;
    const int nt = tile >> 4, bt = tile & 15;
    const int nn = tid & 15, bb = tid >> 4;        // n fastest: coalesced reads
    bf16x8 vh, vl;
    split8(x + ((size_t)(bt*16+bb)*N_IN + nt*16+nn)*8, vh, vl);
    TH[nn*17 + bb] = vh; TL[nn*17 + bb] = vl;
    __syncthreads();
    const int bb2 = tid & 15, nn2 = tid >> 4;      // b fastest: coalesced writes
    const size_t o = (size_t)(nt*16+nn2)*B_ + bt*16 + bb2;
    ((bf16x8*)XH)[o] = TH[nn2*17 + bb2];
    ((bf16x8*)XL)[o] = TL[nn2*17 + bb2];
  }
}

// K-chunk trick: one 16x16x32 MFMA; lane's K-chunk c=l>>4 pulls A from
// [WH,WL,WH,WL] and B from [XH,XH,XL,XL] => exact (Wh+Wl)(xh+xl).
// C layout: col=lane&15=b, row=c*4+e=j.
// MODE 0: uniform coupling 0.1 (applied in pass2's prologue) -> P1
// MODE 1: prologue v1=squash(0.1*sum P1); logits u.v1 -> P2
// MODE 2: prologue veff=squash(0.1*sum P1)+squash(sum P2); logits u.veff -> P3
// Prologue is computed redundantly per block (identical FP order -> deterministic);
// kernel boundary provides cross-XCD visibility of P (no fences, no atomics).
template<int MODE>
__global__ __launch_bounds__(512) void caps_pass(
    const short* __restrict__ WH, const short* __restrict__ WL,
    const short* __restrict__ XH, const short* __restrict__ XL,
    const float* __restrict__ P1, const float* __restrict__ P2,
    float* __restrict__ Pout) {
  __shared__ float vbuf[16*164];                   // padded rows: conflict-light
  __shared__ f32x4 red[4][640];                    // 40 KB tree buffers
  const int tid = threadIdx.x, w = tid >> 6, l = tid & 63;
  const int bb = l & 15, c = l >> 4;
  const int sg = blockIdx.x, bg = blockIdx.y;
  const int b0 = bg*16;
  const int n0 = sg*NPB + w*NPW;
  const short* Abase = (c & 1)  ? WL : WH;
  const short* Bbase = (c >> 1) ? XL : XH;

  const f32x4 zz = {0.f,0.f,0.f,0.f};
  f32x4 acc[N_OUT], vj[N_OUT];
#pragma unroll
  for (int o=0;o<N_OUT;o++) acc[o] = zz;

  if (MODE != 0) {
    // fused finish-of-previous-pass: reduce P over NSG for this bg slice
    const int base = b0*OJ;
#pragma unroll
    for (int k=0;k<5;k++) {
      const int e = tid + k*512;                   // 0..2559; e&15 == lane&15
      float s1 = 0.f;
#pragma unroll 4
      for (int g=0; g<NSG; ++g) s1 += P1[(size_t)g*SN + base + e];
      const float t1 = 0.1f*s1;
      float v = squash_elem(t1);
      if (MODE == 2) {
        float s2 = 0.f;
#pragma unroll 4
        for (int g=0; g<NSG; ++g) s2 += P2[(size_t)g*SN + base + e];
        v += squash_elem(s2);
      }
      vbuf[(e/160)*164 + (e%160)] = v * LOG2E;     // log2 domain for exp2f
    }
    __syncthreads();
#pragma unroll
    for (int o=0;o<N_OUT;o++) vj[o] = *(const f32x4*)&vbuf[bb*164 + o*16 + c*4];
  }

  for (int nn=0; nn<NPW; ++nn) {
    const int n = n0 + nn;
    const bf16x8 bfrag = *(const bf16x8*)&Bbase[((size_t)n*B_ + b0 + bb)*8];
    const short* Ap = &Abase[(size_t)n*1280 + bb*8];
    if (MODE == 0) {
#pragma unroll
      for (int o=0;o<N_OUT;o++) {
        const bf16x8 afrag = *(const bf16x8*)&Ap[o*128];
        acc[o] = __builtin_amdgcn_mfma_f32_16x16x32_bf16(afrag, bfrag, acc[o], 0,0,0);
      }
    } else {
      f32x4 u[N_OUT];
#pragma unroll
      for (int o=0;o<N_OUT;o++) {
        const bf16x8 afrag = *(const bf16x8*)&Ap[o*128];
        u[o] = __builtin_amdgcn_mfma_f32_16x16x32_bf16(afrag, bfrag, zz, 0,0,0);
      }
      float ez[N_OUT], Z = 0.f;
#pragma unroll
      for (int o=0;o<N_OUT;o++) {
        float t = u[o][0]*vj[o][0] + u[o][1]*vj[o][1]
                + u[o][2]*vj[o][2] + u[o][3]*vj[o][3];
        t += __shfl_xor(t, 16);
        t += __shfl_xor(t, 32);
        ez[o] = exp2f(t);                          // veff in log2 domain
        Z += ez[o];
      }
      const float invZ = 1.f / Z;
#pragma unroll
      for (int o=0;o<N_OUT;o++) acc[o] += (ez[o]*invZ) * u[o];
    }
  }

  // 8-wave LDS tree (lane-contiguous 16B slots, conflict-free)
  if (w >= 4) {
#pragma unroll
    for (int o=0;o<N_OUT;o++) red[w-4][o*64 + l] = acc[o];
  }
  __syncthreads();
  if (w < 4) {
#pragma unroll
    for (int o=0;o<N_OUT;o++) acc[o] += red[w][o*64 + l];
  }
  __syncthreads();
  if (w == 2 || w == 3) {
#pragma unroll
    for (int o=0;o<N_OUT;o++) red[w-2][o*64 + l] = acc[o];
  }
  __syncthreads();
  if (w < 2) {
#pragma unroll
    for (int o=0;o<N_OUT;o++) acc[o] += red[w][o*64 + l];
  }
  __syncthreads();
  if (w == 1) {
#pragma unroll
    for (int o=0;o<N_OUT;o++) red[0][o*64 + l] = acc[o];
  }
  __syncthreads();
  if (w == 0) {
    float* Pp = &Pout[(size_t)sg*SN + (size_t)(b0+bb)*OJ + c*4];
#pragma unroll
    for (int o=0;o<N_OUT;o++) {
      acc[o] += red[0][o*64 + l];
      *(f32x4*)&Pp[o*16] = acc[o];
    }
  }
}

// ---- final: out = squash(sum_g P3) ----
__global__ __launch_bounds__(256) void caps_finish(const float* __restrict__ P,
                                                   float* __restrict__ out) {
  const int idx = blockIdx.x*256 + threadIdx.x;    // b*160 + o*16 + j
  float t = 0.f;
#pragma unroll 4
  for (int g=0; g<NSG; ++g) t += P[(size_t)g*SN + idx];
  out[idx] = squash_elem(t);
}

extern "C" void kernel_launch(void* const* d_in, const int* in_sizes, int n_in,
                              void* d_out, int out_size, void* d_ws, size_t ws_size,
                              hipStream_t stream) {
  const float* x = (const float*)d_in[0];   // (256,1152,8)
  const float* W = (const float*)d_in[1];   // (1,1152,10,16,8)
  float* out = (float*)d_out;               // (256,10,16)

  float* P1 = (float*)d_ws;                 // 16*SN floats = 2.6 MB each
  float* P2 = P1 + (size_t)NSG*SN;
  float* P3 = P2 + (size_t)NSG*SN;
  short* WH = (short*)(P3 + (size_t)NSG*SN);
  short* WL = WH + (size_t)NW_ELEMS*8;
  short* XH = WL + (size_t)NW_ELEMS*8;
  short* XL = XH + (size_t)NX_ELEMS*8;      // total ws ~= 23.2 MB

  pack_all<<<NWB + NTILES, 256, 0, stream>>>(W, x, WH, WL, XH, XL);

  const dim3 pg(NSG, 16), pb(512);
  caps_pass<0><<<pg, pb, 0, stream>>>(WH, WL, XH, XL, nullptr, nullptr, P1);
  caps_pass<1><<<pg, pb, 0, stream>>>(WH, WL, XH, XL, P1,      nullptr, P2);
  caps_pass<2><<<pg, pb, 0, stream>>>(WH, WL, XH, XL, P1,      P2,      P3);
  caps_finish<<<SN/256, 256, 0, stream>>>(P3, out);
}

// Round 9
// 97.832 us; speedup vs baseline: 3.5526x; 1.0415x over previous
//
#include <hip/hip_runtime.h>

#define B_ 256
#define N_IN 1152
#define N_OUT 10
#define OJ 160                     // N_OUT * D_OUT
#define SN (B_*OJ)                 // 40960
#define LOG2E 1.44269504088896340736f
#define NSG 72                     // n supergroups (partials)
#define NPB 16                     // n per block
#define NPW 4                      // n per wave (4 waves)
#define NP1 (NSG*16)               // 1152 pass blocks per pass

typedef __attribute__((ext_vector_type(8))) short bf16x8;
typedef __attribute__((ext_vector_type(4))) float f32x4;

#define NW_ELEMS (N_IN*N_OUT*16)   // 184320 rows of 8 (W)
#define NX_ELEMS (B_*N_IN)         // 294912 rows of 8 (x)
#define NWB (NW_ELEMS/256)         // 720 W-pack blocks

// ---- bf16 split helpers (RNE) ----
__device__ __forceinline__ unsigned short f2bf(float f) {
  unsigned u = __float_as_uint(f);
  u += 0x7fffu + ((u >> 16) & 1u);
  return (unsigned short)(u >> 16);
}
__device__ __forceinline__ float bf2f(unsigned short s) {
  return __uint_as_float(((unsigned)s) << 16);
}
__device__ __forceinline__ void split8(const float* p, bf16x8& vh, bf16x8& vl) {
  const float4 a = *(const float4*)p;
  const float4 b = *(const float4*)(p + 4);
  const float w[8] = {a.x,a.y,a.z,a.w,b.x,b.y,b.z,b.w};
#pragma unroll
  for (int e=0;e<8;e++){
    unsigned short hh = f2bf(w[e]);
    vh[e] = (short)hh;
    vl[e] = (short)f2bf(w[e] - bf2f(hh));
  }
}

// ---- DPP rotate-reduce over a 16-lane row ----
template<int CTRL>
__device__ __forceinline__ float dpp_add(float xx) {
  int y = __builtin_amdgcn_mov_dpp(__float_as_int(xx), CTRL, 0xF, 0xF, false);
  return xx + __int_as_float(y);
}
__device__ __forceinline__ float row_sum16(float xx) {
  xx = dpp_add<0x128>(xx); xx = dpp_add<0x124>(xx);
  xx = dpp_add<0x122>(xx); xx = dpp_add<0x121>(xx);
  return xx;
}
__device__ __forceinline__ float squash_elem(float t) {
  const float sq = row_sum16(t * t);
  return t * (sq / (1.f + sq)) * rsqrtf(sq + 1e-8f);
}

// XCD-chunked bijective swizzle: 1152 blocks, 8 XCDs -> each XCD owns a
// contiguous 9-slice sg chunk (W working set 1.5 MB < 4 MB per-XCD L2).
__device__ __forceinline__ void sgbg_map(int bid, int& sg, int& bg) {
  const int xcd = bid & 7, q = bid >> 3;   // q in [0,144)
  sg = xcd*9 + (q >> 4);                   // [0,72)
  bg = q & 15;
}

// K-chunk trick: one 16x16x32 MFMA; lane's K-chunk c=l>>4 pulls A from
// [WH,WL,WH,WL] and B from [XH,XH,XL,XL] => exact (Wh+Wl)(xh+xl).
// C layout: col=lane&15=b, row=c*4+e=j.

// ---- dispatch 1: pass1 on raw f32 (in-register split; emits XH/XL) + W-pack ----
__global__ __launch_bounds__(256) void pass1_fused(
    const float* __restrict__ W, const float* __restrict__ x,
    short* __restrict__ WH, short* __restrict__ WL,
    short* __restrict__ XH, short* __restrict__ XL,
    float* __restrict__ P) {
  const int bid = blockIdx.x, tid = threadIdx.x;
  if (bid >= NP1) {                        // ---- W-pack range ----
    const int t = (bid - NP1)*256 + tid;
    bf16x8 vh, vl; split8(W + (size_t)t*8, vh, vl);
    ((bf16x8*)WH)[t] = vh; ((bf16x8*)WL)[t] = vl;
    return;
  }
  // ---- pass1 range ----
  __shared__ f32x4 red[3*640];             // lane-contiguous tree slots
  int sg, bg; sgbg_map(bid, sg, bg);
  const int w = tid >> 6, l = tid & 63;
  const int bb = l & 15, c = l >> 4;
  const int b0 = bg*16, n0 = sg*NPB + w*NPW;
  const bool useLoA = (c & 1) != 0, useLoB = (c >> 1) != 0;

  const f32x4 zz = {0.f,0.f,0.f,0.f};
  f32x4 acc[N_OUT];
#pragma unroll
  for (int o=0;o<N_OUT;o++) acc[o] = zz;

  for (int nn=0; nn<NPW; ++nn) {
    const int n = n0 + nn;
    // x: load f32, split, persist packed tile, build B-frag
    bf16x8 xh, xl;
    split8(&x[((size_t)(b0+bb)*N_IN + n)*8], xh, xl);
    if (c == 0) ((bf16x8*)XH)[(size_t)n*B_ + b0 + bb] = xh;
    if (c == 2) ((bf16x8*)XL)[(size_t)n*B_ + b0 + bb] = xl;
    const bf16x8 bfrag = useLoB ? xl : xh;
    // W: load f32 rows (j=bb), split, build A-frag
    const float* Wp = &W[(size_t)n*1280 + bb*8];
#pragma unroll
    for (int o=0;o<N_OUT;o++) {
      bf16x8 ah, al;
      split8(Wp + o*128, ah, al);
      const bf16x8 afrag = useLoA ? al : ah;
      acc[o] = __builtin_amdgcn_mfma_f32_16x16x32_bf16(afrag, bfrag, acc[o], 0,0,0);
    }
  }

  // 4-wave LDS tree, lane-contiguous 16B slots (conflict-free)
  if (w) {
#pragma unroll
    for (int o=0;o<N_OUT;o++) red[(w-1)*640 + o*64 + l] = acc[o];
  }
  __syncthreads();
  if (!w) {
    float* Pp = &P[(size_t)sg*SN + (size_t)(b0+bb)*OJ + c*4];
#pragma unroll
    for (int o=0;o<N_OUT;o++) {
      acc[o] += red[o*64+l] + red[640+o*64+l] + red[1280+o*64+l];
      *(f32x4*)&Pp[o*16] = acc[o];
    }
  }
}

// ---- pass 2/3: u via MFMA from packed arrays; logits u.veff (log2 domain) ----
__global__ __launch_bounds__(256) void caps_pass23(
    const short* __restrict__ WH, const short* __restrict__ WL,
    const short* __restrict__ XH, const short* __restrict__ XL,
    const float* __restrict__ veff, float* __restrict__ P) {
  __shared__ f32x4 red[3*640];
  int sg, bg; sgbg_map(blockIdx.x, sg, bg);
  const int tid = threadIdx.x, w = tid >> 6, l = tid & 63;
  const int bb = l & 15, c = l >> 4;
  const int b0 = bg*16;
  const int n0 = sg*NPB + w*NPW;
  const short* Abase = (c & 1)  ? WL : WH;
  const short* Bbase = (c >> 1) ? XL : XH;

  const f32x4 zz = {0.f,0.f,0.f,0.f};
  f32x4 acc[N_OUT], vj[N_OUT];
  const float* vp = &veff[(size_t)(b0+bb)*OJ + c*4];
#pragma unroll
  for (int o=0;o<N_OUT;o++) { vj[o] = *(const f32x4*)&vp[o*16]; acc[o] = zz; }

  for (int nn=0; nn<NPW; ++nn) {
    const int n = n0 + nn;
    const bf16x8 bfrag = *(const bf16x8*)&Bbase[((size_t)n*B_ + b0 + bb)*8];
    const short* Ap = &Abase[(size_t)n*1280 + bb*8];
    f32x4 u[N_OUT];
#pragma unroll
    for (int o=0;o<N_OUT;o++) {
      const bf16x8 afrag = *(const bf16x8*)&Ap[o*128];
      u[o] = __builtin_amdgcn_mfma_f32_16x16x32_bf16(afrag, bfrag, zz, 0,0,0);
    }
    float ez[N_OUT], Z = 0.f;
#pragma unroll
    for (int o=0;o<N_OUT;o++) {
      float t = u[o][0]*vj[o][0] + u[o][1]*vj[o][1]
              + u[o][2]*vj[o][2] + u[o][3]*vj[o][3];
      t += __shfl_xor(t, 16);
      t += __shfl_xor(t, 32);
      ez[o] = exp2f(t);                    // veff stored in log2 domain
      Z += ez[o];
    }
    const float invZ = 1.f / Z;
#pragma unroll
    for (int o=0;o<N_OUT;o++) acc[o] += (ez[o]*invZ) * u[o];
  }

  if (w) {
#pragma unroll
    for (int o=0;o<N_OUT;o++) red[(w-1)*640 + o*64 + l] = acc[o];
  }
  __syncthreads();
  if (!w) {
    float* Pp = &P[(size_t)sg*SN + (size_t)(b0+bb)*OJ + c*4];
#pragma unroll
    for (int o=0;o<N_OUT;o++) {
      acc[o] += red[o*64+l] + red[640+o*64+l] + red[1280+o*64+l];
      *(f32x4*)&Pp[o*16] = acc[o];
    }
  }
}

// ---- reduce partials over NSG + squash (+ optional vprev, output scaling) ----
__global__ __launch_bounds__(256) void caps_finish(const float* __restrict__ P, float scale,
                                                   const float* __restrict__ vprev,
                                                   float* __restrict__ vout, float lscale) {
  const int idx = blockIdx.x*256 + threadIdx.x;      // b*160 + o*16 + j
  float t = 0.f;
#pragma unroll 8
  for (int g=0; g<NSG; ++g) t += P[(size_t)g*SN + idx];
  t *= scale;
  float v = squash_elem(t) * lscale;
  if (vprev != nullptr) v += vprev[idx];
  vout[idx] = v;
}

extern "C" void kernel_launch(void* const* d_in, const int* in_sizes, int n_in,
                              void* d_out, int out_size, void* d_ws, size_t ws_size,
                              hipStream_t stream) {
  const float* x = (const float*)d_in[0];   // (256,1152,8)
  const float* W = (const float*)d_in[1];   // (1,1152,10,16,8)
  float* out = (float*)d_out;               // (256,10,16)

  float* P   = (float*)d_ws;                // NSG*SN floats = 11.8 MB
  float* v1  = P  + (size_t)NSG*SN;         // stored * log2e
  float* v12 = v1 + SN;                     // stored * log2e
  short* WH = (short*)(v12 + SN);
  short* WL = WH + (size_t)NW_ELEMS*8;
  short* XH = WL + (size_t)NW_ELEMS*8;
  short* XL = XH + (size_t)NX_ELEMS*8;      // total ws ~= 27.5 MB

  // d1: pass1 (raw f32, emits XH/XL) + W-pack, one dispatch
  pass1_fused<<<NP1 + NWB, 256, 0, stream>>>(W, x, WH, WL, XH, XL, P);
  // d2: v1 = squash(0.1*s1)*log2e
  caps_finish<<<SN/256, 256, 0, stream>>>(P, 0.1f, nullptr, v1, LOG2E);
  // d3: logits = u.v1 -> P
  caps_pass23<<<NP1, 256, 0, stream>>>(WH, WL, XH, XL, v1, P);
  // d4: v12 = v1 + squash(s2)*log2e
  caps_finish<<<SN/256, 256, 0, stream>>>(P, 1.0f, v1, v12, LOG2E);
  // d5: logits = u.v12 -> P
  caps_pass23<<<NP1, 256, 0, stream>>>(WH, WL, XH, XL, v12, P);
  // d6: out = squash(s3)
  caps_finish<<<SN/256, 256, 0, stream>>>(P, 1.0f, nullptr, out, 1.0f);
}